// Round 1
// 904.283 us; speedup vs baseline: 1.2882x; 1.2882x over previous
//
#include <hip/hip_runtime.h>
#include <cmath>

typedef __bf16 bf16;
typedef __bf16 bf16x4_t __attribute__((ext_vector_type(4)));
typedef __bf16 bf16x8_t __attribute__((ext_vector_type(8)));
typedef float f32x4 __attribute__((ext_vector_type(4)));

#define GAS __attribute__((address_space(1)))
#define LAS __attribute__((address_space(3)))

// ---------------------------------------------------------------------------
// BFP quant-dequant (group=16 along K, m_bit=8) fp32 -> bf16 (values exact).
// Each thread handles 4 consecutive floats (float4); a group of 16 = 4 lanes.
// ---------------------------------------------------------------------------
__global__ __launch_bounds__(256) void bfp_quant_f32_to_bf16(
    const float* __restrict__ x, bf16* __restrict__ y, long long n4) {
  long long t = (long long)blockIdx.x * 256 + threadIdx.x;
  if (t >= n4) return;
  const float4 v = reinterpret_cast<const float4*>(x)[t];

  float a = fmaxf(fmaxf(fabsf(v.x), fabsf(v.y)), fmaxf(fabsf(v.z), fabsf(v.w)));
  a = fmaxf(a, __shfl_xor(a, 1));
  a = fmaxf(a, __shfl_xor(a, 2));   // group max over 4 lanes = 16 elems

  float q0, q1, q2, q3;
  if (a > 0.0f) {
    int ex = (int)((__float_as_uint(a) >> 23) & 0xffu) - 127;
    float scale = ldexpf(1.0f, ex - 7);   // 2^(ex-7)
    float inv   = ldexpf(1.0f, 7 - ex);   // exact power of 2: x*inv == x/scale
    q0 = fminf(fmaxf(rintf(v.x * inv), -127.0f), 127.0f) * scale;
    q1 = fminf(fmaxf(rintf(v.y * inv), -127.0f), 127.0f) * scale;
    q2 = fminf(fmaxf(rintf(v.z * inv), -127.0f), 127.0f) * scale;
    q3 = fminf(fmaxf(rintf(v.w * inv), -127.0f), 127.0f) * scale;
  } else {
    q0 = q1 = q2 = q3 = 0.0f;
  }
  bf16x4_t o = { (__bf16)q0, (__bf16)q1, (__bf16)q2, (__bf16)q3 };
  reinterpret_cast<bf16x4_t*>(y)[t] = o;
}

// ---------------------------------------------------------------------------
// GEMM: C[M,N] = A[M,K] * B[N,K]^T + bias[N], bf16 in / fp32 out.
// 256x256 8-phase template (T1+T2+T3+T4+T5, guide §5):
//   512 threads (8 waves, 2M x 4N), BK=64, 128 KiB double-buffered LDS.
//   Per K-tile: 4 phases, each {ds_read frag-subtile; issue 1 half-tile
//   stage (2x global_load_lds w=16); barrier; lgkmcnt(0); setprio(1);
//   16 MFMA quadrant; setprio(0); barrier}. Counted vmcnt(4) once per
//   K-tile (never 0 in the main loop).
// LDS layout: subtiled [rowtile][ks][16][32] bf16 (1024 B subtiles) with
//   st_16x32 swizzle (byte ^= ((byte>>9)&1)<<5). global_load_lds writes
//   linearly; the swizzle is applied to the per-lane GLOBAL source address
//   and to the ds_read address (both-sides, rule #21).
// Staging schedule (steady state, tile t in buf[t&1]):
//   p1: stage B(t+1).h0 -> buf[~t&1]   (B of tile t-1 dead since t-1.p3)
//   p2: stage B(t+1).h1 -> buf[~t&1]
//   p3: stage A(t+2).h0 -> buf[t&1]    (A of tile t dead after p2 reads)
//   p4: stage A(t+2).h1 -> buf[t&1]; vmcnt(4) -> tile t+1 fully landed,
//       A(t+2)'s 4 loads stay in flight across the barrier.
// Tail: staged k-tile index clamped to NT-1 (uniform counts, junk data
// never read); vmcnt(0) drain after the loop before any LDS could be
// reused by a successor workgroup.
// ---------------------------------------------------------------------------
#define BM 256
#define BN 256
#define BK 64
#define THREADS 512

#define PHASE_SYNC() do {                                   \
    asm volatile("" ::: "memory");                          \
    __builtin_amdgcn_s_barrier();                           \
    asm volatile("s_waitcnt lgkmcnt(0)" ::: "memory");      \
    __builtin_amdgcn_sched_barrier(0);                      \
  } while (0)

#define END_BAR() do {                                      \
    asm volatile("" ::: "memory");                          \
    __builtin_amdgcn_s_barrier();                           \
    asm volatile("" ::: "memory");                          \
  } while (0)

template <int H>
__device__ __forceinline__ void stage_half(const char* gb, char* ldsb,
                                           const int goff[4], long long kb,
                                           int tid) {
#pragma unroll
  for (int i = 2 * H; i < 2 * H + 2; ++i) {
    __builtin_amdgcn_global_load_lds(
        (const GAS unsigned int*)(gb + (goff[i] + kb)),
        (LAS unsigned int*)(ldsb + tid * 16 + i * 8192), 16, 0, 0);
  }
}

__global__ __launch_bounds__(THREADS, 2) void gemm_bf16_bt_8ph(
    const bf16* __restrict__ A,   // [Mc,K] row-major (chunk)
    const bf16* __restrict__ B,   // [N,K] row-major (i.e. B^T of the GEMM)
    const float* __restrict__ bias,
    float* __restrict__ C,        // [Mc,N] row-major (chunk)
    int N, int K) {
  extern __shared__ char smem[];  // 131072 B: [buf][A 32K | B 32K]

  const int tid  = threadIdx.x;
  const int wave = tid >> 6;
  const int lane = tid & 63;
  const int wr   = wave >> 2;     // 0..1 -> 128 rows of C
  const int wc   = wave & 3;      // 0..3 -> 64 cols of C
  const int quad = lane >> 4;     // 0..3
  const int ln   = lane & 15;
  const int NT   = K / BK;

  // T1: bijective XCD swizzle (nwg = 16 * (rows/256), always % 8 == 0).
  const int gx   = gridDim.x;
  const int nwg  = gx * gridDim.y;
  const int orig = blockIdx.y * gx + blockIdx.x;
  const int swz  = (orig & 7) * (nwg >> 3) + (orig >> 3);
  const int bm   = swz / gx;
  const int bn   = swz % gx;

  const long long kstride = (long long)K * 2;
  const char* Ab = (const char*)A + (long long)bm * BM * kstride;
  const char* Bb = (const char*)B + (long long)bn * BN * kstride;

  // Per-lane staging source offsets: LDS linear offset o receives the tile
  // element at the SWIZZLED position (involution), so swizzled ds_reads see
  // the linear tile. Same map for A and B ([256 rows][64 k] bf16, subtiled).
  int goff[4];
#pragma unroll
  for (int i = 0; i < 4; ++i) {
    const int o = tid * 16 + i * 8192;
    const int s = o >> 10;          // subtile 0..31
    int w = o & 1023;
    w ^= ((w >> 9) & 1) << 5;       // st_16x32 swizzle
    const int grow = (s >> 1) * 16 + (w >> 6);
    const int gcb  = (s & 1) * 64 + (w & 63);
    goff[i] = grow * (K * 2) + gcb; // row < 256, K*2*255 ~ 2.1M: fits int
  }
  // Swizzled within-subtile ds_read offset: (ln*64 + quad*16) ^ ((ln>=8)*32)
  const int wofs = (ln * 64 + quad * 16) ^ ((ln & 8) << 2);

  char* const As0 = smem;
  char* const Bs0 = smem + 32768;
  char* const As1 = smem + 65536;
  char* const Bs1 = smem + 98304;

  f32x4 acc[8][4];
#pragma unroll
  for (int m = 0; m < 8; ++m)
#pragma unroll
    for (int n = 0; n < 4; ++n)
      acc[m][n] = (f32x4){0.0f, 0.0f, 0.0f, 0.0f};

  // Prologue: tile 0 fully into buf0; A(1) into buf1 (mimics t=-1 p3/p4).
  stage_half<0>(Ab, As0, goff, 0, tid);
  stage_half<1>(Ab, As0, goff, 0, tid);
  stage_half<0>(Bb, Bs0, goff, 0, tid);
  stage_half<1>(Bb, Bs0, goff, 0, tid);
  {
    const long long k1 = (NT > 1) ? (long long)BK * 2 : 0;
    stage_half<0>(Ab, As1, goff, k1, tid);
    stage_half<1>(Ab, As1, goff, k1, tid);
  }
  asm volatile("s_waitcnt vmcnt(4)" ::: "memory");  // tile 0 landed, A(1) in flight
  __builtin_amdgcn_s_barrier();
  asm volatile("" ::: "memory");

  for (int t = 0; t < NT; ++t) {
    char* const Asc = (t & 1) ? As1 : As0;
    char* const Bsc = (t & 1) ? Bs1 : Bs0;
    char* const Bsn = (t & 1) ? Bs0 : Bs1;
    const long long kbB = (long long)((t + 1 < NT) ? t + 1 : NT - 1) * (BK * 2);
    const long long kbA = (long long)((t + 2 < NT) ? t + 2 : NT - 1) * (BK * 2);

    bf16x8_t a0[4][2], a1[4][2], b0[2][2], b1[2][2];

    // ---- phase 1: read A0 (m 0-3) + B0 (n 0-1); stage B(t+1).h0; Q00
#pragma unroll
    for (int m = 0; m < 4; ++m)
#pragma unroll
      for (int ks = 0; ks < 2; ++ks)
        a0[m][ks] = *(const bf16x8_t*)(Asc + ((((wr * 8 + m) * 2 + ks) << 10) + wofs));
#pragma unroll
    for (int n = 0; n < 2; ++n)
#pragma unroll
      for (int ks = 0; ks < 2; ++ks)
        b0[n][ks] = *(const bf16x8_t*)(Bsc + ((((wc * 4 + n) * 2 + ks) << 10) + wofs));
    stage_half<0>(Bb, Bsn, goff, kbB, tid);
    PHASE_SYNC();
    __builtin_amdgcn_s_setprio(1);
#pragma unroll
    for (int m = 0; m < 4; ++m)
#pragma unroll
      for (int n = 0; n < 2; ++n)
#pragma unroll
        for (int ks = 0; ks < 2; ++ks)
          acc[m][n] = __builtin_amdgcn_mfma_f32_16x16x32_bf16(
              a0[m][ks], b0[n][ks], acc[m][n], 0, 0, 0);
    __builtin_amdgcn_s_setprio(0);
    END_BAR();

    // ---- phase 2: read A1 (m 4-7); stage B(t+1).h1; Q10
#pragma unroll
    for (int m = 0; m < 4; ++m)
#pragma unroll
      for (int ks = 0; ks < 2; ++ks)
        a1[m][ks] = *(const bf16x8_t*)(Asc + ((((wr * 8 + 4 + m) * 2 + ks) << 10) + wofs));
    stage_half<1>(Bb, Bsn, goff, kbB, tid);
    PHASE_SYNC();
    __builtin_amdgcn_s_setprio(1);
#pragma unroll
    for (int m = 0; m < 4; ++m)
#pragma unroll
      for (int n = 0; n < 2; ++n)
#pragma unroll
        for (int ks = 0; ks < 2; ++ks)
          acc[4 + m][n] = __builtin_amdgcn_mfma_f32_16x16x32_bf16(
              a1[m][ks], b0[n][ks], acc[4 + m][n], 0, 0, 0);
    __builtin_amdgcn_s_setprio(0);
    END_BAR();

    // ---- phase 3: read B1 (n 2-3); stage A(t+2).h0 -> CURRENT buf; Q11
#pragma unroll
    for (int n = 0; n < 2; ++n)
#pragma unroll
      for (int ks = 0; ks < 2; ++ks)
        b1[n][ks] = *(const bf16x8_t*)(Bsc + ((((wc * 4 + 2 + n) * 2 + ks) << 10) + wofs));
    stage_half<0>(Ab, Asc, goff, kbA, tid);
    PHASE_SYNC();
    __builtin_amdgcn_s_setprio(1);
#pragma unroll
    for (int m = 0; m < 4; ++m)
#pragma unroll
      for (int n = 0; n < 2; ++n)
#pragma unroll
        for (int ks = 0; ks < 2; ++ks)
          acc[4 + m][2 + n] = __builtin_amdgcn_mfma_f32_16x16x32_bf16(
              a1[m][ks], b1[n][ks], acc[4 + m][2 + n], 0, 0, 0);
    __builtin_amdgcn_s_setprio(0);
    END_BAR();

    // ---- phase 4: stage A(t+2).h1; Q01; counted vmcnt(4)
    stage_half<1>(Ab, Asc, goff, kbA, tid);
    PHASE_SYNC();
    __builtin_amdgcn_s_setprio(1);
#pragma unroll
    for (int m = 0; m < 4; ++m)
#pragma unroll
      for (int n = 0; n < 2; ++n)
#pragma unroll
        for (int ks = 0; ks < 2; ++ks)
          acc[m][2 + n] = __builtin_amdgcn_mfma_f32_16x16x32_bf16(
              a0[m][ks], b1[n][ks], acc[m][2 + n], 0, 0, 0);
    __builtin_amdgcn_s_setprio(0);
    asm volatile("s_waitcnt vmcnt(4)" ::: "memory");  // tile t+1 landed
    END_BAR();
  }
  // Drain the clamped tail stages before the block can exit (their LDS
  // writes must not land in a successor workgroup's LDS).
  asm volatile("s_waitcnt vmcnt(0)" ::: "memory");

  // Epilogue: C/D mapping col = lane&15, row = quad*4 + reg (m89-verified).
  const long long row0 = (long long)bm * BM + wr * 128;
  const int col0 = bn * BN + wc * 64;
#pragma unroll
  for (int n = 0; n < 4; ++n) {
    const int col = col0 + n * 16 + ln;
    const float bv = bias[col];
#pragma unroll
    for (int m = 0; m < 8; ++m) {
      const long long row = row0 + m * 16 + quad * 4;
#pragma unroll
      for (int r = 0; r < 4; ++r)
        C[(row + r) * (long long)N + col] = acc[m][n][r] + bv;
    }
  }
}

extern "C" void kernel_launch(void* const* d_in, const int* in_sizes, int n_in,
                              void* d_out, int out_size, void* d_ws, size_t ws_size,
                              hipStream_t stream) {
  const float* inp    = (const float*)d_in[0];  // [B,S,K] fp32
  const float* weight = (const float*)d_in[1];  // [N,K]   fp32
  const float* bias   = (const float*)d_in[2];  // [N]     fp32
  float* out = (float*)d_out;                   // [B,S,N] fp32

  const int N = in_sizes[2];              // 4096
  const int K = in_sizes[1] / N;          // 4096
  const int M = in_sizes[0] / K;          // 16384

  // Workspace layout:
  //   [0, qw_bytes)   : qw [N,K] bf16  (32 MiB)
  //   [qw_bytes, ...) : qx chunk [Mc,K] bf16, Mc multiple of BM (=256)
  const size_t qw_bytes  = (size_t)N * K * sizeof(bf16);
  const size_t row_bytes = (size_t)K * sizeof(bf16);

  long long Mc;
  if (ws_size >= qw_bytes + (size_t)M * row_bytes) {
    Mc = M;  // everything fits: single GEMM over the full problem
  } else if (ws_size >= qw_bytes + (size_t)BM * row_bytes) {
    Mc = (long long)((ws_size - qw_bytes) / row_bytes) / BM * BM;
  } else {
    Mc = BM;  // desperate floor; requires ws_size >= 34 MiB for correctness
  }

  bf16* qw = (bf16*)d_ws;
  bf16* qx = (bf16*)((char*)d_ws + qw_bytes);

  // 128 KiB dynamic LDS: opt in once (no-op / ignored error on stacks that
  // allow it natively). Host-side call, graph-capture transparent.
  static bool lds_attr_done = false;
  if (!lds_attr_done) {
    (void)hipFuncSetAttribute((const void*)gemm_bf16_bt_8ph,
                              hipFuncAttributeMaxDynamicSharedMemorySize,
                              131072);
    lds_attr_done = true;
  }

  // Quantize weight once (32 MiB bf16).
  const long long n4w = (long long)N * K / 4;
  hipLaunchKernelGGL(bfp_quant_f32_to_bf16, dim3((unsigned)((n4w + 255) / 256)),
                     dim3(256), 0, stream, weight, qw, n4w);

  // Chunk over M: quantize Mc input rows, GEMM them, repeat. Same stream =>
  // serialized; chunk i+1's quant never overlaps chunk i's GEMM reads.
  for (long long m0 = 0; m0 < M; m0 += Mc) {
    const long long rows = (M - m0 < Mc) ? (M - m0) : Mc;
    const long long n4x  = rows * K / 4;
    hipLaunchKernelGGL(bfp_quant_f32_to_bf16, dim3((unsigned)((n4x + 255) / 256)),
                       dim3(256), 0, stream,
                       inp + m0 * K, qx, n4x);
    hipLaunchKernelGGL(gemm_bf16_bt_8ph,
                       dim3(N / BN, (unsigned)(rows / BM)), dim3(THREADS),
                       131072, stream,
                       qx, qw, bias, out + m0 * N, N, K);
  }
}